// Round 13
// baseline (168.115 us; speedup 1.0000x reference)
//
#include <hip/hip_runtime.h>

#define DD 128   // feature dim

typedef unsigned int uint32;
typedef __attribute__((ext_vector_type(8))) short short8;
typedef __attribute__((ext_vector_type(4))) float f32x4;
typedef __attribute__((ext_vector_type(2))) float f32x2;

__device__ __forceinline__ uint32 pack_bf16(float a, float b) {
    uint32 ua = __builtin_bit_cast(uint32, a);
    uint32 ub = __builtin_bit_cast(uint32, b);
    ua = (ua + 0x7fffu + ((ua >> 16) & 1u)) >> 16;   // RNE
    ub = (ub + 0x7fffu + ((ub >> 16) & 1u)) >> 16;
    return ua | (ub << 16);
}

// ---------------- fp8 e4m3 helpers (hw path on gfx950, sw fallback) ----------------
#if __has_builtin(__builtin_amdgcn_cvt_pk_f32_fp8) && __has_builtin(__builtin_amdgcn_cvt_pk_fp8_f32)
#define FP8_HW 1
#else
#define FP8_HW 0
#endif

#if !FP8_HW
__device__ __forceinline__ float fp8_dec1(uint32 b) {
    uint32 s = (b >> 7) & 1, e = (b >> 3) & 15, m = b & 7;
    float v = (e == 0) ? ldexpf((float)m, -9) : ldexpf((float)(8 + m), (int)e - 10);
    return s ? -v : v;
}
__device__ __forceinline__ uint32 fp8_enc1(float x) {
    uint32 u = __builtin_bit_cast(uint32, x);
    uint32 s = (u >> 31) << 7;
    float ax = fabsf(x);
    if (ax >= 448.f) return s | 0x7E;
    if (ax < 0.0009765625f) return s;   // < 2^-10 -> 0
    if (ax >= 0.015625f) {              // normal
        uint32 e = (u >> 23) & 0xFF;
        uint32 m = u & 0x7FFFFF;
        uint32 keep = m >> 20, rest = m & 0xFFFFF;
        keep += (rest > 0x80000u) || (rest == 0x80000u && (keep & 1));
        uint32 ee = e - 127 + 7;
        if (keep == 8) { keep = 0; ee += 1; }
        if (ee > 15 || (ee == 15 && keep > 6)) return s | 0x7E;
        return s | (ee << 3) | keep;
    }
    uint32 ni = (uint32)(ax * 512.f + 0.5f);
    if (ni >= 8) return s | (1u << 3);
    return s | ni;
}
#endif

template <bool WORD>
__device__ __forceinline__ f32x2 fp8x2_dec(uint32 u) {
#if FP8_HW
    return __builtin_amdgcn_cvt_pk_f32_fp8(u, WORD);
#else
    uint32 v = WORD ? (u >> 16) : u;
    f32x2 r; r.x = fp8_dec1(v & 0xff); r.y = fp8_dec1((v >> 8) & 0xff);
    return r;
#endif
}

__device__ __forceinline__ uint32 fp8x4_enc(float4 f) {
#if FP8_HW
    uint32 w = __builtin_amdgcn_cvt_pk_fp8_f32(f.x, f.y, 0, false);
    w = __builtin_amdgcn_cvt_pk_fp8_f32(f.z, f.w, w, true);
    return w;
#else
    return fp8_enc1(f.x) | (fp8_enc1(f.y) << 8) | (fp8_enc1(f.z) << 16) | (fp8_enc1(f.w) << 24);
#endif
}

// ---------------- row_ptr via binary search on sorted edge_row ----------------
__global__ __launch_bounds__(256) void k_row_ptr(const int* __restrict__ row,
                                                 int* __restrict__ rp, int n, int e) {
    int i = blockIdx.x * 256 + threadIdx.x;
    if (i > n) return;
    int lo = 0, hi = e;
    while (lo < hi) { int m = (lo + hi) >> 1; if (row[m] < i) lo = m + 1; else hi = m; }
    rp[i] = lo;
}

// ---------------- prep: feat -> fp8 (gather copy); W1,W2 -> bf16 ----------------
__global__ __launch_bounds__(256) void k_prep(const float* __restrict__ feat,
                                              uint32* __restrict__ featq,
                                              const float* __restrict__ W1,
                                              const float* __restrict__ W2,
                                              uint32* __restrict__ Wb1,
                                              uint32* __restrict__ Wb2, int n) {
    int id = blockIdx.x * 256 + threadIdx.x;
    if (id < n * (DD / 4)) {
        float4 f = ((const float4*)feat)[id];
        featq[id] = fp8x4_enc(f);
    }
    if (id < 2 * DD * DD / 4) {                    // 8192 float4 slots
        int mat = id >> 12, rem = id & 4095;
        float4 wv = ((const float4*)(mat ? W2 : W1))[rem];
        uint2 p;
        p.x = pack_bf16(wv.x, wv.y);
        p.y = pack_bf16(wv.z, wv.w);
        ((uint2*)(mat ? Wb2 : Wb1))[rem] = p;
    }
}

// ---------------- SpMM: one wave per row; 2 edges per gather instruction ----------------
// lane = hi*32 + d32; lane loads uint32 (4 fp8 dims) of row col[e + 2u + hi].
// col/val in wide scalar batches (32 edges: SGPR wide-loads); one cndmask pair per 2 edges.
// Reduce lane^32; lanes 0-31 write.
// PASS 1: out1 = L1x (bf16), out2 = inter (fp8) ; PASS 2: out1 = Linter (bf16)
template <int PASS>
__global__ __launch_bounds__(256) void k_spmm(const int* __restrict__ col,
                                              const float* __restrict__ val,
                                              const uint32* __restrict__ xq,
                                              const int* __restrict__ rp,
                                              const float* __restrict__ feat,
                                              const float* __restrict__ diag,
                                              uint2* __restrict__ out1,
                                              uint32* __restrict__ out2, int n) {
    int lane = threadIdx.x & 63;
    int row = blockIdx.x * 4 + (threadIdx.x >> 6);
    if (row >= n) return;
    row = __builtin_amdgcn_readfirstlane(row);  // wave-uniform -> scalar loads
    int s = rp[row], eend = rp[row + 1];
    uint32 d32 = (uint32)(lane & 31);
    bool hi = lane >= 32;
    f32x2 a01 = {0.f, 0.f}, a23 = {0.f, 0.f};
    int e = s;

#define SPMM_B2(NE)                                                            \
    {                                                                          \
        int c[NE]; float v[NE];                                                \
        _Pragma("unroll")                                                      \
        for (int u = 0; u < NE; ++u) { c[u] = col[e + u]; v[u] = val[e + u]; } \
        uint32 g[NE / 2]; float vs[NE / 2];                                    \
        _Pragma("unroll")                                                      \
        for (int u = 0; u < NE / 2; ++u) {                                     \
            int cs = hi ? c[2 * u + 1] : c[2 * u];                             \
            g[u] = xq[((uint32)cs << 5) + d32];                                \
            vs[u] = hi ? v[2 * u + 1] : v[2 * u];                              \
        }                                                                      \
        _Pragma("unroll")                                                      \
        for (int u = 0; u < NE / 2; ++u) {                                     \
            f32x2 w = {vs[u], vs[u]};                                          \
            a01 += w * fp8x2_dec<false>(g[u]);                                 \
            a23 += w * fp8x2_dec<true >(g[u]);                                 \
        }                                                                      \
    }

    for (; e + 32 <= eend; e += 32) SPMM_B2(32)
    if (e + 16 <= eend) { SPMM_B2(16) e += 16; }
    if (e + 8 <= eend) { SPMM_B2(8) e += 8; }
    if (e + 4 <= eend) { SPMM_B2(4) e += 4; }
    if (e + 2 <= eend) { SPMM_B2(2) e += 2; }
    if (e < eend) {                                // single leftover edge
        int c0 = col[e]; float v0 = val[e];
        uint32 g = xq[((uint32)c0 << 5) + d32];
        float vv = hi ? 0.f : v0;                  // hi half contributes nothing
        f32x2 w = {vv, vv};
        a01 += w * fp8x2_dec<false>(g);
        a23 += w * fp8x2_dec<true >(g);
    }
#undef SPMM_B2

    // reduce the two edge halves (lane ^ 32)
    a01.x += __shfl_xor(a01.x, 32, 64); a01.y += __shfl_xor(a01.y, 32, 64);
    a23.x += __shfl_xor(a23.x, 32, 64); a23.y += __shfl_xor(a23.y, 32, 64);

    if (lane < 32) {                               // lane == d32, owns dims 4*d32..+3
        if (PASS == 1) {
            float dg = diag[row];
            float4 f = ((const float4*)feat)[(size_t)row * 32 + d32];
            uint2 o;
            o.x = pack_bf16(fmaf(dg, f.x, a01.x), fmaf(dg, f.y, a01.y));
            o.y = pack_bf16(fmaf(dg, f.z, a23.x), fmaf(dg, f.w, a23.y));
            out1[(size_t)row * 32 + d32] = o;
            out2[(size_t)row * 32 + d32] =
                fp8x4_enc(make_float4(a01.x * f.x, a01.y * f.y, a23.x * f.z, a23.y * f.w));
        } else {
            uint2 o;
            o.x = pack_bf16(a01.x, a01.y);
            o.y = pack_bf16(a23.x, a23.y);
            out1[(size_t)row * 32 + d32] = o;
        }
    }
}

// ---------------- fused dual GEMM via MFMA: out = A@W1^T + B@W2^T + b1 + b2 ----------------
__global__ __launch_bounds__(512, 2) void k_gemm(const uint32* __restrict__ Abf,
                                                 const uint32* __restrict__ Bbf,
                                                 const uint32* __restrict__ Wb1g,
                                                 const uint32* __restrict__ Wb2g,
                                                 const float* __restrict__ b1,
                                                 const float* __restrict__ b2,
                                                 float* __restrict__ out, int n) {
    __shared__ __align__(16) char lds[65536];   // Wb1 @0, Wb2 @32768 (32 KB each)
    int t = threadIdx.x;
    {
        const uint2* s1 = (const uint2*)Wb1g;
        const uint2* s2 = (const uint2*)Wb2g;
#pragma unroll
        for (int u = 0; u < 16; ++u) {
            int id = u * 512 + t;                  // 0..8191 uint2 slots
            int j = id >> 5, kq = id & 31;
            int dst = j * 256 + ((kq * 8) ^ ((j & 7) << 4));
            *(uint2*)(lds + dst) = s1[id];
            *(uint2*)(lds + 32768 + dst) = s2[id];
        }
    }
    __syncthreads();
    int lane = t & 63, w = t >> 6;
    int g = lane >> 4;                             // k-chunk group 0..3
    int rowbase = blockIdx.x * 256 + w * 32;
    int rr = rowbase + (lane & 15);
    int r0 = min(rr, n - 1);
    int r1 = min(rr + 16, n - 1);
    const uint4* A4 = (const uint4*)Abf;           // 16 uint4 per row
    const uint4* B4 = (const uint4*)Bbf;

    f32x4 acc[2][8];
#pragma unroll
    for (int mt = 0; mt < 2; ++mt)
#pragma unroll
        for (int jt = 0; jt < 8; ++jt) acc[mt][jt] = (f32x4){0.f, 0.f, 0.f, 0.f};

    uint4 a0 = A4[(size_t)r0 * 16 + g], a1 = A4[(size_t)r1 * 16 + g];
    uint4 c0 = B4[(size_t)r0 * 16 + g], c1 = B4[(size_t)r1 * 16 + g];
#pragma unroll
    for (int kc = 0; kc < 4; ++kc) {
        uint4 na0, na1, nc0, nc1;
        if (kc < 3) {
            na0 = A4[(size_t)r0 * 16 + (kc + 1) * 4 + g];
            na1 = A4[(size_t)r1 * 16 + (kc + 1) * 4 + g];
            nc0 = B4[(size_t)r0 * 16 + (kc + 1) * 4 + g];
            nc1 = B4[(size_t)r1 * 16 + (kc + 1) * 4 + g];
        }
        short8 fa0 = __builtin_bit_cast(short8, a0);
        short8 fa1 = __builtin_bit_cast(short8, a1);
        short8 fc0 = __builtin_bit_cast(short8, c0);
        short8 fc1 = __builtin_bit_cast(short8, c1);
        int kbase = kc * 64 + g * 16;
#pragma unroll
        for (int jt = 0; jt < 8; ++jt) {
            int j = jt * 16 + (lane & 15);
            int off = j * 256 + (kbase ^ ((j & 7) << 4));
            short8 w1 = *(const short8*)(lds + off);
            short8 w2 = *(const short8*)(lds + 32768 + off);
            acc[0][jt] = __builtin_amdgcn_mfma_f32_16x16x32_bf16(fa0, w1, acc[0][jt], 0, 0, 0);
            acc[0][jt] = __builtin_amdgcn_mfma_f32_16x16x32_bf16(fc0, w2, acc[0][jt], 0, 0, 0);
            acc[1][jt] = __builtin_amdgcn_mfma_f32_16x16x32_bf16(fa1, w1, acc[1][jt], 0, 0, 0);
            acc[1][jt] = __builtin_amdgcn_mfma_f32_16x16x32_bf16(fc1, w2, acc[1][jt], 0, 0, 0);
        }
        a0 = na0; a1 = na1; c0 = nc0; c1 = nc1;
    }
    float bsum[8];
#pragma unroll
    for (int jt = 0; jt < 8; ++jt) {
        int cj = jt * 16 + (lane & 15);
        bsum[jt] = b1[cj] + b2[cj];
    }
#pragma unroll
    for (int mt = 0; mt < 2; ++mt) {
#pragma unroll
        for (int i = 0; i < 4; ++i) {
            int r = rowbase + mt * 16 + g * 4 + i;
            if (r < n) {
                float* orow = out + (size_t)r * DD;
#pragma unroll
                for (int jt = 0; jt < 8; ++jt)
                    orow[jt * 16 + (lane & 15)] = acc[mt][jt][i] + bsum[jt];
            }
        }
    }
}

extern "C" void kernel_launch(void* const* d_in, const int* in_sizes, int n_in,
                              void* d_out, int out_size, void* d_ws, size_t ws_size,
                              hipStream_t stream) {
    const int*   edge_row = (const int*)d_in[0];
    const int*   edge_col = (const int*)d_in[1];
    const float* edge_val = (const float*)d_in[2];
    const float* diag     = (const float*)d_in[3];
    const float* feat     = (const float*)d_in[4];
    const float* W1       = (const float*)d_in[5];
    const float* b1       = (const float*)d_in[6];
    const float* W2       = (const float*)d_in[7];
    const float* b2       = (const float*)d_in[8];
    float* out = (float*)d_out;

    const int E = in_sizes[0];
    const int N = in_sizes[3];

    // workspace layout
    char* ws = (char*)d_ws;
    size_t off = 0;
    int* rp            = (int*)(ws + off);      off += (((size_t)(N + 1) * 4) + 255) & ~(size_t)255;
    uint32* featq      = (uint32*)(ws + off);   off += (size_t)N * (DD / 4) * 4;   // fp8 x
    uint32* interq     = (uint32*)(ws + off);   off += (size_t)N * (DD / 4) * 4;   // fp8 inter
    uint32* L1xbf      = (uint32*)(ws + off);   off += (size_t)N * (DD / 2) * 4;
    uint32* Linterbf   = (uint32*)(ws + off);   off += (size_t)N * (DD / 2) * 4;
    uint32* Wb1g       = (uint32*)(ws + off);   off += (size_t)DD * (DD / 2) * 4;
    uint32* Wb2g       = (uint32*)(ws + off);   off += (size_t)DD * (DD / 2) * 4;
    (void)ws_size; (void)n_in; (void)out_size;

    // 1. row_ptr
    k_row_ptr<<<(N + 1 + 255) / 256, 256, 0, stream>>>(edge_row, rp, N, E);
    // 2. prep: feat -> fp8, W -> bf16
    {
        int work = N * (DD / 4);
        if (work < 2 * DD * DD / 4) work = 2 * DD * DD / 4;
        k_prep<<<(work + 255) / 256, 256, 0, stream>>>(feat, featq, W1, W2, Wb1g, Wb2g, N);
    }
    // 3. SpMM pass 1: L1x (bf16), inter (fp8)
    k_spmm<1><<<(N + 3) / 4, 256, 0, stream>>>(edge_col, edge_val, featq, rp,
                                               feat, diag, (uint2*)L1xbf, interq, N);
    // 4. SpMM pass 2: Linter (bf16)
    k_spmm<2><<<(N + 3) / 4, 256, 0, stream>>>(edge_col, edge_val, interq, rp,
                                               nullptr, nullptr, (uint2*)Linterbf, nullptr, N);
    // 5. fused dual GEMM + bias (MFMA)
    k_gemm<<<(N + 255) / 256, 512, 0, stream>>>(L1xbf, Linterbf, Wb1g, Wb2g, b1, b2, out, N);
}

// Round 14
// 164.049 us; speedup vs baseline: 1.0248x; 1.0248x over previous
//
#include <hip/hip_runtime.h>

#define DD 128   // feature dim

typedef unsigned int uint32;
typedef __attribute__((ext_vector_type(8))) short short8;
typedef __attribute__((ext_vector_type(4))) float f32x4;
typedef __attribute__((ext_vector_type(2))) float f32x2;

__device__ __forceinline__ uint32 pack_bf16(float a, float b) {
    uint32 ua = __builtin_bit_cast(uint32, a);
    uint32 ub = __builtin_bit_cast(uint32, b);
    ua = (ua + 0x7fffu + ((ua >> 16) & 1u)) >> 16;   // RNE
    ub = (ub + 0x7fffu + ((ub >> 16) & 1u)) >> 16;
    return ua | (ub << 16);
}

// ---------------- fp8 e4m3 helpers (hw path on gfx950, sw fallback) ----------------
#if __has_builtin(__builtin_amdgcn_cvt_pk_f32_fp8) && __has_builtin(__builtin_amdgcn_cvt_pk_fp8_f32)
#define FP8_HW 1
#else
#define FP8_HW 0
#endif

#if !FP8_HW
__device__ __forceinline__ float fp8_dec1(uint32 b) {
    uint32 s = (b >> 7) & 1, e = (b >> 3) & 15, m = b & 7;
    float v = (e == 0) ? ldexpf((float)m, -9) : ldexpf((float)(8 + m), (int)e - 10);
    return s ? -v : v;
}
__device__ __forceinline__ uint32 fp8_enc1(float x) {
    uint32 u = __builtin_bit_cast(uint32, x);
    uint32 s = (u >> 31) << 7;
    float ax = fabsf(x);
    if (ax >= 448.f) return s | 0x7E;
    if (ax < 0.0009765625f) return s;   // < 2^-10 -> 0
    if (ax >= 0.015625f) {              // normal
        uint32 e = (u >> 23) & 0xFF;
        uint32 m = u & 0x7FFFFF;
        uint32 keep = m >> 20, rest = m & 0xFFFFF;
        keep += (rest > 0x80000u) || (rest == 0x80000u && (keep & 1));
        uint32 ee = e - 127 + 7;
        if (keep == 8) { keep = 0; ee += 1; }
        if (ee > 15 || (ee == 15 && keep > 6)) return s | 0x7E;
        return s | (ee << 3) | keep;
    }
    uint32 ni = (uint32)(ax * 512.f + 0.5f);
    if (ni >= 8) return s | (1u << 3);
    return s | ni;
}
#endif

template <bool WORD>
__device__ __forceinline__ f32x2 fp8x2_dec(uint32 u) {
#if FP8_HW
    return __builtin_amdgcn_cvt_pk_f32_fp8(u, WORD);
#else
    uint32 v = WORD ? (u >> 16) : u;
    f32x2 r; r.x = fp8_dec1(v & 0xff); r.y = fp8_dec1((v >> 8) & 0xff);
    return r;
#endif
}

__device__ __forceinline__ uint32 fp8x4_enc(float4 f) {
#if FP8_HW
    uint32 w = __builtin_amdgcn_cvt_pk_fp8_f32(f.x, f.y, 0, false);
    w = __builtin_amdgcn_cvt_pk_fp8_f32(f.z, f.w, w, true);
    return w;
#else
    return fp8_enc1(f.x) | (fp8_enc1(f.y) << 8) | (fp8_enc1(f.z) << 16) | (fp8_enc1(f.w) << 24);
#endif
}

// ---------------- row_ptr via binary search on sorted edge_row ----------------
__global__ __launch_bounds__(256) void k_row_ptr(const int* __restrict__ row,
                                                 int* __restrict__ rp, int n, int e) {
    int i = blockIdx.x * 256 + threadIdx.x;
    if (i > n) return;
    int lo = 0, hi = e;
    while (lo < hi) { int m = (lo + hi) >> 1; if (row[m] < i) lo = m + 1; else hi = m; }
    rp[i] = lo;
}

// ---------------- prep: feat -> fp8 (gather copy); W1,W2 -> bf16 ----------------
__global__ __launch_bounds__(256) void k_prep(const float* __restrict__ feat,
                                              uint32* __restrict__ featq,
                                              const float* __restrict__ W1,
                                              const float* __restrict__ W2,
                                              uint32* __restrict__ Wb1,
                                              uint32* __restrict__ Wb2, int n) {
    int id = blockIdx.x * 256 + threadIdx.x;
    if (id < n * (DD / 4)) {
        float4 f = ((const float4*)feat)[id];
        featq[id] = fp8x4_enc(f);
    }
    if (id < 2 * DD * DD / 4) {                    // 8192 float4 slots
        int mat = id >> 12, rem = id & 4095;
        float4 wv = ((const float4*)(mat ? W2 : W1))[rem];
        uint2 p;
        p.x = pack_bf16(wv.x, wv.y);
        p.y = pack_bf16(wv.z, wv.w);
        ((uint2*)(mat ? Wb2 : Wb1))[rem] = p;
    }
}

// ---------------- SpMM: one wave per row; 2 edges per gather instruction ----------------
// lane = hi*32 + d32; lane loads uint32 (4 fp8 dims) of row col[e + 2u + hi].
// col/val in wide scalar batches (16 edges); one cndmask pair per 2 edges.
// Reduce lane^32; lanes 0-31 write.
// PASS 1: out1 = L1x (bf16), out2 = inter (fp8) ; PASS 2: out1 = Linter (bf16)
template <int PASS>
__global__ __launch_bounds__(256) void k_spmm(const int* __restrict__ col,
                                              const float* __restrict__ val,
                                              const uint32* __restrict__ xq,
                                              const int* __restrict__ rp,
                                              const float* __restrict__ feat,
                                              const float* __restrict__ diag,
                                              uint2* __restrict__ out1,
                                              uint32* __restrict__ out2, int n) {
    int lane = threadIdx.x & 63;
    int row = blockIdx.x * 4 + (threadIdx.x >> 6);
    if (row >= n) return;
    row = __builtin_amdgcn_readfirstlane(row);  // wave-uniform -> scalar loads
    int s = rp[row], eend = rp[row + 1];
    uint32 d32 = (uint32)(lane & 31);
    bool hi = lane >= 32;
    f32x2 a01 = {0.f, 0.f}, a23 = {0.f, 0.f};
    int e = s;

#define SPMM_B2(NE)                                                            \
    {                                                                          \
        int c[NE]; float v[NE];                                                \
        _Pragma("unroll")                                                      \
        for (int u = 0; u < NE; ++u) { c[u] = col[e + u]; v[u] = val[e + u]; } \
        uint32 g[NE / 2]; float vs[NE / 2];                                    \
        _Pragma("unroll")                                                      \
        for (int u = 0; u < NE / 2; ++u) {                                     \
            int cs = hi ? c[2 * u + 1] : c[2 * u];                             \
            g[u] = xq[((uint32)cs << 5) + d32];                                \
            vs[u] = hi ? v[2 * u + 1] : v[2 * u];                              \
        }                                                                      \
        _Pragma("unroll")                                                      \
        for (int u = 0; u < NE / 2; ++u) {                                     \
            f32x2 w = {vs[u], vs[u]};                                          \
            a01 += w * fp8x2_dec<false>(g[u]);                                 \
            a23 += w * fp8x2_dec<true >(g[u]);                                 \
        }                                                                      \
    }

    for (; e + 16 <= eend; e += 16) SPMM_B2(16)
    if (e + 8 <= eend) { SPMM_B2(8) e += 8; }
    if (e + 4 <= eend) { SPMM_B2(4) e += 4; }
    if (e + 2 <= eend) { SPMM_B2(2) e += 2; }
    if (e < eend) {                                // single leftover edge
        int c0 = col[e]; float v0 = val[e];
        uint32 g = xq[((uint32)c0 << 5) + d32];
        float vv = hi ? 0.f : v0;                  // hi half contributes nothing
        f32x2 w = {vv, vv};
        a01 += w * fp8x2_dec<false>(g);
        a23 += w * fp8x2_dec<true >(g);
    }
#undef SPMM_B2

    // reduce the two edge halves (lane ^ 32)
    a01.x += __shfl_xor(a01.x, 32, 64); a01.y += __shfl_xor(a01.y, 32, 64);
    a23.x += __shfl_xor(a23.x, 32, 64); a23.y += __shfl_xor(a23.y, 32, 64);

    if (lane < 32) {                               // lane == d32, owns dims 4*d32..+3
        if (PASS == 1) {
            float dg = diag[row];
            float4 f = ((const float4*)feat)[(size_t)row * 32 + d32];
            uint2 o;
            o.x = pack_bf16(fmaf(dg, f.x, a01.x), fmaf(dg, f.y, a01.y));
            o.y = pack_bf16(fmaf(dg, f.z, a23.x), fmaf(dg, f.w, a23.y));
            out1[(size_t)row * 32 + d32] = o;
            out2[(size_t)row * 32 + d32] =
                fp8x4_enc(make_float4(a01.x * f.x, a01.y * f.y, a23.x * f.z, a23.y * f.w));
        } else {
            uint2 o;
            o.x = pack_bf16(a01.x, a01.y);
            o.y = pack_bf16(a23.x, a23.y);
            out1[(size_t)row * 32 + d32] = o;
        }
    }
}

// ---------------- fused dual GEMM via MFMA: out = A@W1^T + B@W2^T + b1 + b2 ----------------
__global__ __launch_bounds__(512, 2) void k_gemm(const uint32* __restrict__ Abf,
                                                 const uint32* __restrict__ Bbf,
                                                 const uint32* __restrict__ Wb1g,
                                                 const uint32* __restrict__ Wb2g,
                                                 const float* __restrict__ b1,
                                                 const float* __restrict__ b2,
                                                 float* __restrict__ out, int n) {
    __shared__ __align__(16) char lds[65536];   // Wb1 @0, Wb2 @32768 (32 KB each)
    int t = threadIdx.x;
    {
        const uint2* s1 = (const uint2*)Wb1g;
        const uint2* s2 = (const uint2*)Wb2g;
#pragma unroll
        for (int u = 0; u < 16; ++u) {
            int id = u * 512 + t;                  // 0..8191 uint2 slots
            int j = id >> 5, kq = id & 31;
            int dst = j * 256 + ((kq * 8) ^ ((j & 7) << 4));
            *(uint2*)(lds + dst) = s1[id];
            *(uint2*)(lds + 32768 + dst) = s2[id];
        }
    }
    __syncthreads();
    int lane = t & 63, w = t >> 6;
    int g = lane >> 4;                             // k-chunk group 0..3
    int rowbase = blockIdx.x * 256 + w * 32;
    int rr = rowbase + (lane & 15);
    int r0 = min(rr, n - 1);
    int r1 = min(rr + 16, n - 1);
    const uint4* A4 = (const uint4*)Abf;           // 16 uint4 per row
    const uint4* B4 = (const uint4*)Bbf;

    f32x4 acc[2][8];
#pragma unroll
    for (int mt = 0; mt < 2; ++mt)
#pragma unroll
        for (int jt = 0; jt < 8; ++jt) acc[mt][jt] = (f32x4){0.f, 0.f, 0.f, 0.f};

    uint4 a0 = A4[(size_t)r0 * 16 + g], a1 = A4[(size_t)r1 * 16 + g];
    uint4 c0 = B4[(size_t)r0 * 16 + g], c1 = B4[(size_t)r1 * 16 + g];
#pragma unroll
    for (int kc = 0; kc < 4; ++kc) {
        uint4 na0, na1, nc0, nc1;
        if (kc < 3) {
            na0 = A4[(size_t)r0 * 16 + (kc + 1) * 4 + g];
            na1 = A4[(size_t)r1 * 16 + (kc + 1) * 4 + g];
            nc0 = B4[(size_t)r0 * 16 + (kc + 1) * 4 + g];
            nc1 = B4[(size_t)r1 * 16 + (kc + 1) * 4 + g];
        }
        short8 fa0 = __builtin_bit_cast(short8, a0);
        short8 fa1 = __builtin_bit_cast(short8, a1);
        short8 fc0 = __builtin_bit_cast(short8, c0);
        short8 fc1 = __builtin_bit_cast(short8, c1);
        int kbase = kc * 64 + g * 16;
#pragma unroll
        for (int jt = 0; jt < 8; ++jt) {
            int j = jt * 16 + (lane & 15);
            int off = j * 256 + (kbase ^ ((j & 7) << 4));
            short8 w1 = *(const short8*)(lds + off);
            short8 w2 = *(const short8*)(lds + 32768 + off);
            acc[0][jt] = __builtin_amdgcn_mfma_f32_16x16x32_bf16(fa0, w1, acc[0][jt], 0, 0, 0);
            acc[0][jt] = __builtin_amdgcn_mfma_f32_16x16x32_bf16(fc0, w2, acc[0][jt], 0, 0, 0);
            acc[1][jt] = __builtin_amdgcn_mfma_f32_16x16x32_bf16(fa1, w1, acc[1][jt], 0, 0, 0);
            acc[1][jt] = __builtin_amdgcn_mfma_f32_16x16x32_bf16(fc1, w2, acc[1][jt], 0, 0, 0);
        }
        a0 = na0; a1 = na1; c0 = nc0; c1 = nc1;
    }
    float bsum[8];
#pragma unroll
    for (int jt = 0; jt < 8; ++jt) {
        int cj = jt * 16 + (lane & 15);
        bsum[jt] = b1[cj] + b2[cj];
    }
#pragma unroll
    for (int mt = 0; mt < 2; ++mt) {
#pragma unroll
        for (int i = 0; i < 4; ++i) {
            int r = rowbase + mt * 16 + g * 4 + i;
            if (r < n) {
                float* orow = out + (size_t)r * DD;
#pragma unroll
                for (int jt = 0; jt < 8; ++jt)
                    orow[jt * 16 + (lane & 15)] = acc[mt][jt][i] + bsum[jt];
            }
        }
    }
}

extern "C" void kernel_launch(void* const* d_in, const int* in_sizes, int n_in,
                              void* d_out, int out_size, void* d_ws, size_t ws_size,
                              hipStream_t stream) {
    const int*   edge_row = (const int*)d_in[0];
    const int*   edge_col = (const int*)d_in[1];
    const float* edge_val = (const float*)d_in[2];
    const float* diag     = (const float*)d_in[3];
    const float* feat     = (const float*)d_in[4];
    const float* W1       = (const float*)d_in[5];
    const float* b1       = (const float*)d_in[6];
    const float* W2       = (const float*)d_in[7];
    const float* b2       = (const float*)d_in[8];
    float* out = (float*)d_out;

    const int E = in_sizes[0];
    const int N = in_sizes[3];

    // workspace layout
    char* ws = (char*)d_ws;
    size_t off = 0;
    int* rp            = (int*)(ws + off);      off += (((size_t)(N + 1) * 4) + 255) & ~(size_t)255;
    uint32* featq      = (uint32*)(ws + off);   off += (size_t)N * (DD / 4) * 4;   // fp8 x
    uint32* interq     = (uint32*)(ws + off);   off += (size_t)N * (DD / 4) * 4;   // fp8 inter
    uint32* L1xbf      = (uint32*)(ws + off);   off += (size_t)N * (DD / 2) * 4;
    uint32* Linterbf   = (uint32*)(ws + off);   off += (size_t)N * (DD / 2) * 4;
    uint32* Wb1g       = (uint32*)(ws + off);   off += (size_t)DD * (DD / 2) * 4;
    uint32* Wb2g       = (uint32*)(ws + off);   off += (size_t)DD * (DD / 2) * 4;
    (void)ws_size; (void)n_in; (void)out_size;

    // 1. row_ptr
    k_row_ptr<<<(N + 1 + 255) / 256, 256, 0, stream>>>(edge_row, rp, N, E);
    // 2. prep: feat -> fp8, W -> bf16
    {
        int work = N * (DD / 4);
        if (work < 2 * DD * DD / 4) work = 2 * DD * DD / 4;
        k_prep<<<(work + 255) / 256, 256, 0, stream>>>(feat, featq, W1, W2, Wb1g, Wb2g, N);
    }
    // 3. SpMM pass 1: L1x (bf16), inter (fp8)
    k_spmm<1><<<(N + 3) / 4, 256, 0, stream>>>(edge_col, edge_val, featq, rp,
                                               feat, diag, (uint2*)L1xbf, interq, N);
    // 4. SpMM pass 2: Linter (bf16)
    k_spmm<2><<<(N + 3) / 4, 256, 0, stream>>>(edge_col, edge_val, interq, rp,
                                               nullptr, nullptr, (uint2*)Linterbf, nullptr, N);
    // 5. fused dual GEMM + bias (MFMA)
    k_gemm<<<(N + 255) / 256, 512, 0, stream>>>(L1xbf, Linterbf, Wb1g, Wb2g, b1, b2, out, N);
}